// Round 1
// baseline (61.618 us; speedup 1.0000x reference)
//
#include <hip/hip_runtime.h>
#include <math.h>

#define F_SIZE 26
#define F2 676
#define A 5
#define NUM_CLASSES 80
#define T 32
#define NB 128
#define CELLS (F2*A)              // 3380
#define BLOCKS_PER_BATCH 4
#define CHUNK (CELLS/BLOCKS_PER_BATCH)  // 845
#define OBJECT_SCALE 5.0f

__global__ __launch_bounds__(256) void yolo_main(
    const float* __restrict__ feat,
    const float* __restrict__ box_pred,
    const float* __restrict__ box_conf,
    const float* __restrict__ box_prob,
    const float* __restrict__ targets,
    const float* __restrict__ anchors,
    double* __restrict__ partial)
{
    __shared__ float tc0[T], tc1[T], tc2[T], tc3[T];  // target corners
    __shared__ float tarea[T];
    __shared__ float tmv[T][5];
    __shared__ int   tpos[T], tbp[T];
    __shared__ int   match[CELLS];
    __shared__ double red[256];

    const int tid = threadIdx.x;
    const int b = blockIdx.x / BLOCKS_PER_BATCH;
    const int chunk = blockIdx.x % BLOCKS_PER_BATCH;

    // init match table
    for (int i = tid; i < CELLS; i += 256) match[i] = -1;

    // per-target precompute (32 threads)
    if (tid < T) {
        const float* tg = targets + ((size_t)b*T + tid)*5;
        float x1 = tg[0], y1 = tg[1], x2 = tg[2], y2 = tg[3], cls = tg[4];
        tc0[tid]=x1; tc1[tid]=y1; tc2[tid]=x2; tc3[tid]=y2;
        tarea[tid] = (x2-x1)*(y2-y1);
        float cx = (x1+x2)*(F_SIZE*0.5f);
        float cy = (y1+y2)*(F_SIZE*0.5f);
        float tw = (x2-x1)*(float)F_SIZE;
        float th = (y2-y1)*(float)F_SIZE;
        float fx = floorf(cx), fy = floorf(cy);
        int pos = (int)(fy*(float)F_SIZE + fx);
        // argmax over anchors of IoU(origin-centered target box, anchor box)
        int best = 0; float bestiou = -1.0f;
        for (int a2 = 0; a2 < A; a2++){
            float aw = anchors[a2*2+0], ah = anchors[a2*2+1];
            float inter = fminf(tw, aw) * fminf(th, ah);
            float u = tw*th + aw*ah - inter;
            float iou = inter / u;
            if (iou > bestiou){ bestiou = iou; best = a2; }   // first-max tie-break
        }
        tpos[tid] = pos; tbp[tid] = best;
        tmv[tid][0] = cx - fx;
        tmv[tid][1] = cy - fy;
        tmv[tid][2] = logf(tw / anchors[best*2+0]);
        tmv[tid][3] = logf(th / anchors[best*2+1]);
        tmv[tid][4] = cls;
    }
    __syncthreads();
    if (tid < T) {
        // last-wins scatter: larger target index wins (matches XLA update order)
        atomicMax(&match[tpos[tid]*A + tbp[tid]], tid);
    }
    __syncthreads();

    double acc = 0.0;
    const size_t base = (size_t)b * CELLS;
    const int iend = (chunk+1)*CHUNK;
    for (int i = chunk*CHUNK + tid; i < iend; i += 256) {
        const float4 bp = *(const float4*)(box_pred + (base + i)*4);
        float px1 = bp.x - bp.z*0.5f, px2 = bp.x + bp.z*0.5f;
        float py1 = bp.y - bp.w*0.5f, py2 = bp.y + bp.w*0.5f;
        float parea = bp.z * bp.w;
        float best = 0.0f;
        #pragma unroll
        for (int t = 0; t < T; t++){
            float iw = fminf(px2, tc2[t]) - fmaxf(px1, tc0[t]);
            float ih = fminf(py2, tc3[t]) - fmaxf(py1, tc1[t]);
            iw = fmaxf(iw, 0.0f); ih = fmaxf(ih, 0.0f);
            float inter = iw * ih;
            float iou = inter / (parea + tarea[t] - inter);
            best = fmaxf(best, iou);
        }
        float conf = box_conf[base + i];
        int m = match[i];
        if (m >= 0) {
            // conf_mask overridden to OBJECT_SCALE, pos_mask = 1
            float d = OBJECT_SCALE * (conf - 1.0f);
            acc += 0.5 * (double)(d*d);
            // loc loss: box_match = [sig(f0), sig(f1), f2, f3]
            const float4 f = *(const float4*)(feat + (base + i)*4);
            float s0 = 1.0f/(1.0f + expf(-f.x));
            float s1 = 1.0f/(1.0f + expf(-f.y));
            float d0 = s0  - tmv[m][0];
            float d1 = s1  - tmv[m][1];
            float d2 = f.z - tmv[m][2];
            float d3 = f.w - tmv[m][3];
            acc += 0.5 * (double)(d0*d0 + d1*d1 + d2*d2 + d3*d3);
            // class loss: lse - picked
            const float* pp = box_prob + (base + i)*(size_t)NUM_CLASSES;
            float mx = pp[0];
            for (int c = 1; c < NUM_CLASSES; c++) mx = fmaxf(mx, pp[c]);
            float s = 0.0f;
            for (int c = 0; c < NUM_CLASSES; c++) s += expf(pp[c] - mx);
            float lse = mx + logf(s);
            int lab = (int)tmv[m][4];
            acc += (double)(lse - pp[lab]);
        } else if (!(best > 0.5f)) {
            acc += 0.5 * (double)(conf*conf);
        }
        // best > 0.5 and unmatched -> conf_mask = 0 -> no contribution
    }

    red[tid] = acc;
    __syncthreads();
    for (int s = 128; s > 0; s >>= 1){
        if (tid < s) red[tid] += red[tid + s];
        __syncthreads();
    }
    if (tid == 0) partial[blockIdx.x] = red[0];
}

__global__ __launch_bounds__(256) void yolo_reduce(const double* __restrict__ partial,
                                                   float* __restrict__ out)
{
    __shared__ double red[256];
    int tid = threadIdx.x;
    double a = 0.0;
    for (int i = tid; i < NB*BLOCKS_PER_BATCH; i += 256) a += partial[i];
    red[tid] = a;
    __syncthreads();
    for (int s = 128; s > 0; s >>= 1){
        if (tid < s) red[tid] += red[tid + s];
        __syncthreads();
    }
    if (tid == 0) out[0] = (float)(red[0] / (double)NB);
}

extern "C" void kernel_launch(void* const* d_in, const int* in_sizes, int n_in,
                              void* d_out, int out_size, void* d_ws, size_t ws_size,
                              hipStream_t stream) {
    const float* feat     = (const float*)d_in[0];
    const float* box_pred = (const float*)d_in[1];
    const float* box_conf = (const float*)d_in[2];
    const float* box_prob = (const float*)d_in[3];
    const float* targets  = (const float*)d_in[4];
    const float* anchors  = (const float*)d_in[5];
    double* partial = (double*)d_ws;   // 512 doubles, fully overwritten each launch
    float* out = (float*)d_out;

    yolo_main<<<NB*BLOCKS_PER_BATCH, 256, 0, stream>>>(
        feat, box_pred, box_conf, box_prob, targets, anchors, partial);
    yolo_reduce<<<1, 256, 0, stream>>>(partial, out);
}

// Round 2
// 19.538 us; speedup vs baseline: 3.1538x; 3.1538x over previous
//
#include <hip/hip_runtime.h>
#include <math.h>

#define F_SIZE 26
#define F2 676
#define A 5
#define NUM_CLASSES 80
#define T 32
#define NB 128
#define CELLS (F2*A)               // 3380
#define CBLK 14                    // background blocks per batch (14*256 = 3584 >= 3380)
#define NC_BLOCKS (NB*CBLK)        // 1792
#define BBLK 8                     // matched blocks per batch (8 blocks x 4 waves = 32 targets)
#define NMB_BLOCKS (NB*BBLK)       // 1024
#define NPART (NC_BLOCKS + NMB_BLOCKS)

__global__ __launch_bounds__(256) void yolo_fused(
    const float* __restrict__ feat,
    const float* __restrict__ box_pred,
    const float* __restrict__ box_conf,
    const float* __restrict__ box_prob,
    const float* __restrict__ targets,
    const float* __restrict__ anchors,
    double* __restrict__ partial)
{
    const int tid = threadIdx.x;
    double acc = 0.0;

    __shared__ float4 tc[T];
    __shared__ float  ta[T];
    __shared__ double red[256];

    if (blockIdx.x < NC_BLOCKS) {
        // ---------------- background role: one thread per cell ----------------
        const int b = blockIdx.x / CBLK;
        const int chunk = blockIdx.x % CBLK;
        if (tid < T) {
            const float* tg = targets + ((size_t)b*T + tid)*5;
            float x1 = tg[0], y1 = tg[1], x2 = tg[2], y2 = tg[3];
            tc[tid] = make_float4(x1, y1, x2, y2);
            ta[tid] = (x2 - x1) * (y2 - y1);
        }
        __syncthreads();
        const int i = chunk*256 + tid;
        if (i < CELLS) {
            const size_t idx = (size_t)b*CELLS + i;
            const float4 p = *(const float4*)(box_pred + idx*4);
            float px1 = p.x - p.z*0.5f, px2 = p.x + p.z*0.5f;
            float py1 = p.y - p.w*0.5f, py2 = p.y + p.w*0.5f;
            float parea = p.z * p.w;
            bool covered = false;
            #pragma unroll
            for (int t = 0; t < T; t++) {
                float4 c = tc[t];
                float iw = fminf(px2, c.z) - fmaxf(px1, c.x);
                float ih = fminf(py2, c.w) - fmaxf(py1, c.y);
                iw = fmaxf(iw, 0.0f); ih = fmaxf(ih, 0.0f);
                float inter = iw * ih;
                // best_iou > 0.5  <=>  exists t: inter/(pa+ta-inter) > 0.5  <=>  3*inter > pa+ta
                covered = covered || (3.0f*inter > parea + ta[t]);
            }
            if (!covered) {
                float conf = box_conf[idx];
                acc = 0.5 * (double)(conf*conf);
            }
        }
    } else {
        // ---------------- matched role: one wave per target ----------------
        const int bb = blockIdx.x - NC_BLOCKS;
        const int b  = bb >> 3;               // / BBLK
        const int lane = tid & 63;
        const int wid  = tid >> 6;
        const int t = ((bb & 7) << 2) + wid;  // 0..31: this wave's target
        const int l = lane & 31;              // lanes 32-63 duplicate 0-31

        const float* tg = targets + ((size_t)b*T + l)*5;
        float x1 = tg[0], y1 = tg[1], x2 = tg[2], y2 = tg[3], cls = tg[4];
        float cx = (x1+x2)*(F_SIZE*0.5f), cy = (y1+y2)*(F_SIZE*0.5f);
        float tw = (x2-x1)*(float)F_SIZE,  th = (y2-y1)*(float)F_SIZE;
        float fx = floorf(cx), fy = floorf(cy);
        int pos = (int)(fy*(float)F_SIZE + fx);
        int bp = 0; float bi = -1.0f;
        #pragma unroll
        for (int a2 = 0; a2 < A; a2++) {
            float aw = anchors[a2*2+0], ah = anchors[a2*2+1];
            float inter = fminf(tw, aw) * fminf(th, ah);
            float iou = inter / (tw*th + aw*ah - inter);
            if (iou > bi) { bi = iou; bp = a2; }   // first-max tie-break (argmax)
        }

        const int my_pos = __shfl(pos, t);
        const int my_bp  = __shfl(bp,  t);
        // last-wins scatter: a higher-index target with the same slot beats us
        bool lose = __ballot((lane < T) && (lane > t) && (pos == my_pos) && (bp == my_bp)) != 0ULL;

        if (!lose) {
            // uniform mvals for target t
            float X1 = __shfl(x1, t), Y1 = __shfl(y1, t);
            float X2 = __shfl(x2, t), Y2 = __shfl(y2, t);
            float MC = __shfl(cls, t);
            float mcx = (X1+X2)*(F_SIZE*0.5f), mcy = (Y1+Y2)*(F_SIZE*0.5f);
            float mtw = (X2-X1)*(float)F_SIZE, mth = (Y2-Y1)*(float)F_SIZE;
            float mv0 = mcx - floorf(mcx), mv1 = mcy - floorf(mcy);
            float mv2 = logf(mtw / anchors[my_bp*2+0]);
            float mv3 = logf(mth / anchors[my_bp*2+1]);

            const size_t idx = (size_t)b*CELLS + (size_t)(my_pos*A + my_bp);

            // recompute covered-bool for this cell, bit-identical to background role
            const float4 p = *(const float4*)(box_pred + idx*4);
            float px1 = p.x - p.z*0.5f, px2 = p.x + p.z*0.5f;
            float py1 = p.y - p.w*0.5f, py2 = p.y + p.w*0.5f;
            float parea = p.z * p.w;
            float iw = fminf(px2, x2) - fmaxf(px1, x1);
            float ih = fminf(py2, y2) - fmaxf(py1, y1);
            iw = fmaxf(iw, 0.0f); ih = fmaxf(ih, 0.0f);
            float inter = iw * ih;
            float tarea = (x2 - x1) * (y2 - y1);
            bool covered = __ballot((lane < T) && (3.0f*inter > parea + tarea)) != 0ULL;

            // conf: matched term, minus compensation for background role's add
            float conf = box_conf[idx];
            float df = 5.0f * (conf - 1.0f);
            acc = 0.5 * (double)(df*df);
            if (!covered) acc -= 0.5 * (double)(conf*conf);

            // loc loss
            const float4 f = *(const float4*)(feat + idx*4);
            float s0 = 1.0f/(1.0f + expf(-f.x));
            float s1 = 1.0f/(1.0f + expf(-f.y));
            float d0 = s0  - mv0, d1 = s1  - mv1;
            float d2 = f.z - mv2, d3 = f.w - mv3;
            acc += 0.5 * (double)(d0*d0 + d1*d1 + d2*d2 + d3*d3);

            // class loss: wave-parallel LSE over 80 logits
            const float* pp = box_prob + idx*(size_t)NUM_CLASSES;
            float v0 = pp[lane];
            float v1 = (lane < 16) ? pp[64 + lane] : -3.0e38f;
            float mxv = fmaxf(v0, v1);
            #pragma unroll
            for (int o = 32; o >= 1; o >>= 1) mxv = fmaxf(mxv, __shfl_xor(mxv, o));
            float se = expf(v0 - mxv) + ((lane < 16) ? expf(v1 - mxv) : 0.0f);
            #pragma unroll
            for (int o = 32; o >= 1; o >>= 1) se += __shfl_xor(se, o);
            float lse = mxv + logf(se);
            float picked = pp[(int)MC];
            acc += (double)(lse - picked);

            if (lane != 0) acc = 0.0;   // wave contributes once
        }
    }

    // block reduction (256 doubles)
    red[tid] = acc;
    __syncthreads();
    for (int s = 128; s > 0; s >>= 1) {
        if (tid < s) red[tid] += red[tid + s];
        __syncthreads();
    }
    if (tid == 0) partial[blockIdx.x] = red[0];
}

__global__ __launch_bounds__(256) void yolo_reduce(const double* __restrict__ partial,
                                                   float* __restrict__ out)
{
    __shared__ double red[256];
    const int tid = threadIdx.x;
    double a = 0.0;
    for (int i = tid; i < NPART; i += 256) a += partial[i];
    red[tid] = a;
    __syncthreads();
    for (int s = 128; s > 0; s >>= 1) {
        if (tid < s) red[tid] += red[tid + s];
        __syncthreads();
    }
    if (tid == 0) out[0] = (float)(red[0] / (double)NB);
}

extern "C" void kernel_launch(void* const* d_in, const int* in_sizes, int n_in,
                              void* d_out, int out_size, void* d_ws, size_t ws_size,
                              hipStream_t stream) {
    const float* feat     = (const float*)d_in[0];
    const float* box_pred = (const float*)d_in[1];
    const float* box_conf = (const float*)d_in[2];
    const float* box_prob = (const float*)d_in[3];
    const float* targets  = (const float*)d_in[4];
    const float* anchors  = (const float*)d_in[5];
    double* partial = (double*)d_ws;   // NPART doubles, fully overwritten each launch
    float* out = (float*)d_out;

    yolo_fused<<<NPART, 256, 0, stream>>>(
        feat, box_pred, box_conf, box_prob, targets, anchors, partial);
    yolo_reduce<<<1, 256, 0, stream>>>(partial, out);
}